// Round 5
// baseline (242.371 us; speedup 1.0000x reference)
//
#include <hip/hip_runtime.h>
#include <math.h>

#define N 4096
#define D 128
#define RPB 8            // rows per block == waves per block
#define NT 512
#define KSEL 32          // 0-indexed order statistic (33rd smallest)
#define CAND 192         // collect band (KSEL, CAND]
#define ALPHA_C 16.0f
#define KROWS 64         // rows per knorm block

__device__ inline float waveSumF(float v){
  #pragma unroll
  for (int o = 32; o; o >>= 1) v += __shfl_xor(v, o);
  return v;
}
__device__ inline int waveSumI(int v){
  #pragma unroll
  for (int o = 32; o; o >>= 1) v += __shfl_xor(v, o);
  return v;
}
__device__ inline float waveMinF(float v){
  #pragma unroll
  for (int o = 32; o; o >>= 1) v = fminf(v, __shfl_xor(v, o));
  return v;
}
// order-preserving float<->uint key (monotone bijection)
__device__ inline unsigned fkey(float f){
  unsigned u = __float_as_uint(f);
  return u ^ ((u >> 31) ? 0xFFFFFFFFu : 0x80000000u);
}
__device__ inline float fkey_inv(unsigned u){
  unsigned bits = (u & 0x80000000u) ? (u ^ 0x80000000u) : ~u;
  return __uint_as_float(bits);
}

// --- kernel 1: normalize 64 rows/block; coalesced xnT via padded LDS tile
__global__ __launch_bounds__(256) void knorm(const float* __restrict__ in,
                                             float* __restrict__ xn,
                                             float* __restrict__ xnT,
                                             float* __restrict__ sq,
                                             double* __restrict__ accum,
                                             unsigned* __restrict__ ctr){
  __shared__ float tile[KROWS][D + 1];     // 33 KB, pad kills bank conflicts
  const int w = threadIdx.x >> 6, lane = threadIdx.x & 63;
  const int r0 = blockIdx.x * KROWS;

  if (blockIdx.x == 0 && threadIdx.x < 5){
    if (threadIdx.x < 4) accum[threadIdx.x] = 0.0;
    else *ctr = 0u;
  }

  for (int it = 0; it < 16; ++it){
    int rl = w * 16 + it;
    int row = r0 + rl;
    const float* p = in + (size_t)row * D;
    float e0 = p[lane], e1 = p[lane + 64];
    float s = waveSumF(e0*e0 + e1*e1);
    float inv = 1.0f / sqrtf(s);
    float x0 = e0 * inv, x1 = e1 * inv;
    float s2 = waveSumF(x0*x0 + x1*x1);    // faithful: sq from normalized x
    xn[(size_t)row * D + lane]      = x0;
    xn[(size_t)row * D + lane + 64] = x1;
    tile[rl][lane] = x0; tile[rl][lane + 64] = x1;
    if (lane == 0) sq[row] = s2;
  }
  __syncthreads();
  // wave w writes k = 32w..32w+31; 64 consecutive floats per store (coalesced)
  for (int kk = 0; kk < 32; ++kk){
    int k = 32 * w + kk;
    xnT[(size_t)k * N + r0 + lane] = tile[lane][k];   // bank (lane+k)%32: clean
  }
}

// --- kernel 2: two-half dot pass + register transpose + selection + logits
__global__ __launch_bounds__(NT, 3) void kmain(const float* __restrict__ xn,
                                               const float* __restrict__ xnT,
                                               const float* __restrict__ sq,
                                               const int* __restrict__ tgt,
                                               double* __restrict__ accum,
                                               unsigned* __restrict__ ctr,
                                               float* __restrict__ out){
  __shared__ float xi[RPB][D];            // 4 KB
  __shared__ float buf[2][RPB][256];      // 16 KB transpose tiles (dbuf)
  __shared__ float cand[RPB][CAND];       // 6 KB
  __shared__ int   ccnt[RPB];
  __shared__ float scrB[RPB][RPB];        // [src wave][row] base partials
  __shared__ float scrM[RPB][RPB];        // [src wave][row] minpos partials
  __shared__ float scrP[RPB], scrN[RPB], lsSh[RPB], acSh[RPB];

  const int tid  = threadIdx.x;
  const int lane = tid & 63;
  const int w    = tid >> 6;              // wave id == owned row in per-wave phase
  const int i0   = blockIdx.x * RPB;

  for (int t = tid; t < RPB * D; t += NT)
    (&xi[0][0])[t] = xn[(size_t)i0 * D + t];
  if (lane == 0){
    ccnt[w] = 0;
    #pragma unroll
    for (int t = 0; t < RPB; ++t){ scrB[w][t] = 0.f; scrM[w][t] = INFINITY; }
  }
  __syncthreads();

  const float4* T4 = (const float4*)xnT;
  float d[64];                            // wave w's full dist row, d[4*(2wp+h)+q]
  float posd = 0.f, negd = 0.f;

  #pragma unroll
  for (int h = 0; h < 2; ++h){
    // ---- dot pass, half h: lane owns j = 4f..4f+3, f = 128w + 64h + lane
    const int f = 128 * w + 64 * h + lane;
    float acc[RPB][4];
    #pragma unroll
    for (int r = 0; r < RPB; ++r)
      #pragma unroll
      for (int q = 0; q < 4; ++q) acc[r][q] = 0.f;

    for (int k = 0; k < D; ++k){
      float4 v = T4[(size_t)k * (N/4) + f];
      float xik[RPB];
      #pragma unroll
      for (int r = 0; r < RPB; ++r) xik[r] = xi[r][k];   // LDS broadcast
      #pragma unroll
      for (int r = 0; r < RPB; ++r){
        acc[r][0] += xik[r] * v.x;  acc[r][1] += xik[r] * v.y;
        acc[r][2] += xik[r] * v.z;  acc[r][3] += xik[r] * v.w;
      }
    }

    // ---- 8 transpose rounds: round t materializes row t (this half) in LDS;
    // wave t pulls its 2048 values -> d[32] ; stats fused.
    const float4 sq4 = ((const float4*)sq)[f];
    const int4   tg4 = ((const int4*)tgt)[f];
    const int jbase = 4 * f;

    #pragma unroll
    for (int t = 0; t < RPB; ++t){
      const int A = t & 1;
      const float sqi_t = sq[i0 + t];      // block-uniform scalar
      const int   ti_t  = tgt[i0 + t];
      float dv[4]; float pb = 0.f, pm = INFINITY;
      #pragma unroll
      for (int q = 0; q < 4; ++q){
        float sqjq = (q==0)?sq4.x:(q==1)?sq4.y:(q==2)?sq4.z:sq4.w;
        int   tjq  = (q==0)?tg4.x:(q==1)?tg4.y:(q==2)?tg4.z:tg4.w;
        float dj = sqi_t + sqjq - 2.0f * acc[t][q];
        pb += dj;                          // base includes true diag value (ref)
        bool same = (tjq == ti_t);
        bool diag = (jbase + q == i0 + t);
        if (same && !diag){ posd += dj; pm = fminf(pm, dj); }
        if (!same) negd += dj;
        dv[q] = diag ? INFINITY : dj;
      }
      float rb = waveSumF(pb);
      float rm = waveMinF(pm);
      if (lane == 0){ scrB[w][t] += rb; scrM[w][t] = fminf(scrM[w][t], rm); }
      ((float4*)&buf[A][w][4*lane])[0] = make_float4(dv[0], dv[1], dv[2], dv[3]);
      __syncthreads();
      if (w == t){
        #pragma unroll
        for (int wp = 0; wp < RPB; ++wp){
          float4 v = ((const float4*)&buf[A][wp][4*lane])[0];
          d[4*(2*wp + h) + 0] = v.x;  d[4*(2*wp + h) + 1] = v.y;
          d[4*(2*wp + h) + 2] = v.z;  d[4*(2*wp + h) + 3] = v.w;
        }
      }
      // alternate buffer next round; that round's __syncthreads protects reuse
    }
  }

  { float v = waveSumF(posd); if (lane == 0) scrP[w] = v; }
  { float v = waveSumF(negd); if (lane == 0) scrN[w] = v; }
  __syncthreads();

  // per-wave cross-wave-reduced stats for its own row
  float base, minpos;
  {
    float bp = (lane < 8) ? scrB[lane][w] : 0.f;
    base = waveSumF(bp) * (1.0f / (float)N);
    float mp = (lane < 8) ? scrM[lane][w] : INFINITY;
    minpos = waveMinF(mp);
  }
  if (tid == 0){
    double sp = 0.0, sn = 0.0;
    #pragma unroll
    for (int r = 0; r < RPB; ++r){ sp += (double)scrP[r]; sn += (double)scrN[r]; }
    atomicAdd(&accum[2], sp);
    atomicAdd(&accum[3], sn);
  }

  // ---- selection from registers (wave-local; exact R4 logic, proven)
  float thr;
  {
    float dmin = INFINITY;
    #pragma unroll
    for (int s = 0; s < 64; ++s) dmin = fminf(dmin, d[s]);
    dmin = waveMinF(dmin);

    unsigned lo = fkey(dmin);              // cnt(d < dmin) == 0 < 33
    unsigned hi = fkey(4.5f);              // all real dists <= 4 -> cnt >= 33
    int c = 0; bool have = false; float pvx = 0.f;

    while (hi - lo > 1u){
      float loV = fkey_inv(lo), hiV = fkey_inv(hi);
      unsigned mid = fkey(0.5f * (loV + hiV));       // value-space pivot
      mid = (mid <= lo) ? lo + 1u : ((mid >= hi) ? hi - 1u : mid);
      float pv = fkey_inv(mid);
      int cc = 0;
      #pragma unroll
      for (int s = 0; s < 64; ++s) cc += (d[s] < pv) ? 1 : 0;
      cc = waveSumI(cc);
      if (cc < KSEL + 1) lo = mid;
      else { hi = mid; if (cc <= CAND){ c = cc; have = true; pvx = pv; break; } }
    }

    if (have){
      #pragma unroll
      for (int s = 0; s < 64; ++s){
        if (d[s] < pvx){
          int ix = atomicAdd(&ccnt[w], 1);
          if (ix < CAND) cand[w][ix] = d[s];
        }
      }
      __threadfence_block();
      #pragma unroll
      for (int m = 0; m < 3; ++m){
        int idx = lane + 64 * m;
        if (idx < c){
          float v = cand[w][idx];
          int rank = 0;
          for (int q2 = 0; q2 < c; ++q2){
            float cq = cand[w][q2];                  // LDS broadcast
            rank += (cq < v) || (cq == v && q2 < idx);
          }
          if (rank == KSEL) lsSh[w] = v;             // unique-winner mailbox
        }
      }
      __threadfence_block();
      thr = lsSh[w];
    } else {
      thr = fkey_inv(lo);                            // exact 33rd smallest
    }
  }

  // ---- logits for row w (strict '<', diag is INF)
  {
    const int tw = tgt[i0 + w];
    float pls = 0.f, nls = 0.f; int pcnt = 0;
    #pragma unroll
    for (int u = 0; u < 16; ++u){
      int4 tg = ((const int4*)tgt)[64 * u + lane];
      #pragma unroll
      for (int q = 0; q < 4; ++q){
        float dvq = d[4*u + q];
        int   tjq = (q==0)?tg.x:(q==1)?tg.y:(q==2)?tg.z:tg.w;
        if (dvq < thr){
          float e = expf(ALPHA_C * (base - dvq));
          if (tjq == tw){ pls += e; pcnt++; } else nls += e;
        }
      }
    }
    pls = waveSumF(pls); nls = waveSumF(nls); pcnt = waveSumI(pcnt);
    if (lane == 0){
      float plogit = (pcnt > 0) ? pls : expf(ALPHA_C * (base - minpos));
      float li = -logf(plogit / (plogit + nls));
      lsSh[w] = li;
      acSh[w] = (li < 0.6f) ? 1.f : 0.f;
    }
  }
  __syncthreads();
  if (tid == 0){
    float ls = 0.f, ac = 0.f;
    #pragma unroll
    for (int r = 0; r < RPB; ++r){ ls += lsSh[r]; ac += acSh[r]; }
    atomicAdd(&accum[0], (double)ls);
    atomicAdd(&accum[1], (double)ac);
    // last-block finalize
    __threadfence();
    unsigned done = atomicAdd(ctr, 1u);
    if (done == gridDim.x - 1){
      double a0 = atomicAdd(&accum[0], 0.0);
      double a1 = atomicAdd(&accum[1], 0.0);
      double a2 = atomicAdd(&accum[2], 0.0);
      double a3 = atomicAdd(&accum[3], 0.0);
      out[0] = (float)(a0 / (double)N);
      out[1] = (float)(a1 / (double)N);
      out[2] = (float)(a2 / ((double)N * 7.0));
      out[3] = (float)(a3 / ((double)N * (double)(N - 8)));
    }
  }
}

extern "C" void kernel_launch(void* const* d_in, const int* in_sizes, int n_in,
                              void* d_out, int out_size, void* d_ws, size_t ws_size,
                              hipStream_t stream){
  (void)in_sizes; (void)n_in; (void)out_size; (void)ws_size;
  const float* in  = (const float*)d_in[0];
  const int*   tgt = (const int*)d_in[1];
  float* out = (float*)d_out;

  float*    xn    = (float*)d_ws;                    // N*D floats (2 MB)
  float*    xnT   = xn  + (size_t)N * D;             // D*N floats (2 MB)
  float*    sq    = xnT + (size_t)N * D;             // N floats
  double*   accum = (double*)(sq + N);               // 4 doubles (8B aligned)
  unsigned* ctr   = (unsigned*)(accum + 4);

  knorm <<<N/KROWS, 256, 0, stream>>>(in, xn, xnT, sq, accum, ctr);
  kmain <<<N/RPB, NT, 0, stream>>>(xn, xnT, sq, tgt, accum, ctr, out);
}

// Round 6
// 187.985 us; speedup vs baseline: 1.2893x; 1.2893x over previous
//
#include <hip/hip_runtime.h>
#include <math.h>

#define N 4096
#define D 128
#define RPB 8            // rows per block == waves per block
#define NT 512
#define KSEL 32          // 0-indexed order statistic (33rd smallest)
#define CAND 192         // collect band (KSEL, CAND]
#define ALPHA_C 16.0f
#define KROWS 32         // rows per knorm block

__device__ inline float waveSumF(float v){
  #pragma unroll
  for (int o = 32; o; o >>= 1) v += __shfl_xor(v, o);
  return v;
}
__device__ inline int waveSumI(int v){
  #pragma unroll
  for (int o = 32; o; o >>= 1) v += __shfl_xor(v, o);
  return v;
}
__device__ inline float waveMinF(float v){
  #pragma unroll
  for (int o = 32; o; o >>= 1) v = fminf(v, __shfl_xor(v, o));
  return v;
}
// order-preserving float<->uint key (monotone bijection)
__device__ inline unsigned fkey(float f){
  unsigned u = __float_as_uint(f);
  return u ^ ((u >> 31) ? 0xFFFFFFFFu : 0x80000000u);
}
__device__ inline float fkey_inv(unsigned u){
  unsigned bits = (u & 0x80000000u) ? (u ^ 0x80000000u) : ~u;
  return __uint_as_float(bits);
}

// --- kernel 1: normalize 32 rows/block (128 blocks); coalesced xnT via LDS tile
__global__ __launch_bounds__(256) void knorm(const float* __restrict__ in,
                                             float* __restrict__ xn,
                                             float* __restrict__ xnT,
                                             float* __restrict__ sq,
                                             double* __restrict__ accum,
                                             unsigned* __restrict__ ctr){
  __shared__ float tile[KROWS][D + 1];
  const int w = threadIdx.x >> 6, lane = threadIdx.x & 63;
  const int r0 = blockIdx.x * KROWS;

  if (blockIdx.x == 0 && threadIdx.x < 5){
    if (threadIdx.x < 4) accum[threadIdx.x] = 0.0;
    else *ctr = 0u;
  }

  for (int it = 0; it < 8; ++it){
    int rl = w * 8 + it;
    int row = r0 + rl;
    const float* p = in + (size_t)row * D;
    float e0 = p[lane], e1 = p[lane + 64];
    float s = waveSumF(e0*e0 + e1*e1);
    float inv = 1.0f / sqrtf(s);
    float x0 = e0 * inv, x1 = e1 * inv;
    float s2 = waveSumF(x0*x0 + x1*x1);    // faithful: sq from normalized x
    xn[(size_t)row * D + lane]      = x0;
    xn[(size_t)row * D + lane + 64] = x1;
    tile[rl][lane] = x0; tile[rl][lane + 64] = x1;
    if (lane == 0) sq[row] = s2;
  }
  __syncthreads();
  // wave w writes k in [32w, 32w+32); 2 half-waves do k, k+1 (128B segments)
  #pragma unroll
  for (int kk = 0; kk < 16; ++kk){
    int k = 32 * w + 2 * kk + (lane >> 5);
    xnT[(size_t)k * N + r0 + (lane & 31)] = tile[lane & 31][k];
  }
}

// --- kernel 2 (main path): dot->global dist + stats, then readback selection
__global__ __launch_bounds__(NT, 4) void kmain(const float* __restrict__ xn,
                                               const float* __restrict__ xnT,
                                               const float* __restrict__ sq,
                                               const int* __restrict__ tgt,
                                               float* __restrict__ dist,
                                               double* __restrict__ accum,
                                               unsigned* __restrict__ ctr,
                                               float* __restrict__ out){
  __shared__ float xi[RPB][D];            // 4 KB
  __shared__ float cand[RPB][CAND];       // 6 KB
  __shared__ int   ccnt[RPB];
  __shared__ float scrB[RPB][RPB];        // [wave][row] base partials
  __shared__ float scrM[RPB][RPB];        // [wave][row] minpos partials
  __shared__ float scrP[RPB], scrN[RPB];
  __shared__ float baseSh[RPB], minposSh[RPB], thrSh[RPB], lsSh[RPB], acSh[RPB];

  const int tid  = threadIdx.x;
  const int lane = tid & 63;
  const int w    = tid >> 6;              // wave id == owned row in phase 4
  const int i0   = blockIdx.x * RPB;

  for (int t = tid; t < RPB * D; t += NT)
    (&xi[0][0])[t] = xn[(size_t)i0 * D + t];
  if (lane == 0) ccnt[w] = 0;
  __syncthreads();

  // ---- phase 1: dot pass, single sweep. Lane owns cols 4fA..4fA+3, 4fB..4fB+3
  const int fA = 128 * w + lane;          // float4 col index
  const int fB = fA + 64;
  const float4* T4 = (const float4*)xnT;

  float acc[RPB][8];
  #pragma unroll
  for (int r = 0; r < RPB; ++r)
    #pragma unroll
    for (int q = 0; q < 8; ++q) acc[r][q] = 0.f;

  #pragma unroll 1
  for (int kc = 0; kc < D/4; ++kc){
    float4 xi4[RPB];
    #pragma unroll
    for (int r = 0; r < RPB; ++r) xi4[r] = ((const float4*)xi[r])[kc];  // b128 broadcast
    #pragma unroll
    for (int kk = 0; kk < 4; ++kk){
      const int k = 4*kc + kk;
      float4 vA = T4[(size_t)k * (N/4) + fA];
      float4 vB = T4[(size_t)k * (N/4) + fB];
      #pragma unroll
      for (int r = 0; r < RPB; ++r){
        float xik = (kk==0)?xi4[r].x:(kk==1)?xi4[r].y:(kk==2)?xi4[r].z:xi4[r].w;
        acc[r][0] += xik * vA.x;  acc[r][1] += xik * vA.y;
        acc[r][2] += xik * vA.z;  acc[r][3] += xik * vA.w;
        acc[r][4] += xik * vB.x;  acc[r][5] += xik * vB.y;
        acc[r][6] += xik * vB.z;  acc[r][7] += xik * vB.w;
      }
    }
  }

  // ---- phase 2: dist + stats + global store (no transpose)
  {
    const float4 sqA = ((const float4*)sq)[fA], sqB = ((const float4*)sq)[fB];
    const int4   tgA = ((const int4*)tgt)[fA], tgB = ((const int4*)tgt)[fB];
    float sqj[8] = {sqA.x,sqA.y,sqA.z,sqA.w, sqB.x,sqB.y,sqB.z,sqB.w};
    int   tj [8] = {tgA.x,tgA.y,tgA.z,tgA.w, tgB.x,tgB.y,tgB.z,tgB.w};
    float posd = 0.f, negd = 0.f;

    #pragma unroll
    for (int r = 0; r < RPB; ++r){
      const float sqi_r = sq[i0 + r];      // block-uniform
      const int   ti_r  = tgt[i0 + r];
      float dv[8]; float pb = 0.f, pm = INFINITY;
      #pragma unroll
      for (int q = 0; q < 8; ++q){
        int j = (q < 4) ? (4*fA + q) : (4*fB + q - 4);
        float dj = sqi_r + sqj[q] - 2.0f * acc[r][q];
        pb += dj;                          // base includes true diag value (ref)
        bool same = (tj[q] == ti_r);
        bool diag = (j == i0 + r);
        if (same && !diag){ posd += dj; pm = fminf(pm, dj); }
        if (!same) negd += dj;
        dv[q] = diag ? INFINITY : dj;
      }
      float rb = waveSumF(pb);
      float rm = waveMinF(pm);
      if (lane == 0){ scrB[w][r] = rb; scrM[w][r] = rm; }
      float* drp = dist + (size_t)(i0 + r) * N;
      ((float4*)(drp + 4*fA))[0] = make_float4(dv[0], dv[1], dv[2], dv[3]);
      ((float4*)(drp + 4*fB))[0] = make_float4(dv[4], dv[5], dv[6], dv[7]);
    }
    { float v = waveSumF(posd); if (lane == 0) scrP[w] = v; }
    { float v = waveSumF(negd); if (lane == 0) scrN[w] = v; }
  }
  __syncthreads();                         // dist rows complete + scr filled

  if (tid < RPB){
    float s = 0.f, m = INFINITY;
    #pragma unroll
    for (int q = 0; q < RPB; ++q){ s += scrB[q][tid]; m = fminf(m, scrM[q][tid]); }
    baseSh[tid]   = s * (1.0f / (float)N);
    minposSh[tid] = m;
  }
  if (tid == 0){
    double sp = 0.0, sn = 0.0;
    #pragma unroll
    for (int r = 0; r < RPB; ++r){ sp += (double)scrP[r]; sn += (double)scrN[r]; }
    atomicAdd(&accum[2], sp);
    atomicAdd(&accum[3], sn);
  }
  __syncthreads();

  // ---- phase 3: readback own row (L2/L3-hot, coalesced) into registers
  float d[64];
  {
    const float4* drow = (const float4*)(dist + (size_t)(i0 + w) * N);
    #pragma unroll
    for (int u = 0; u < 16; ++u){
      float4 v = drow[64*u + lane];
      d[4*u+0] = v.x; d[4*u+1] = v.y; d[4*u+2] = v.z; d[4*u+3] = v.w;
    }
  }
  const float base   = baseSh[w];
  const float minpos = minposSh[w];

  // ---- phase 4: selection from registers (R4/R5-proven logic)
  float thr;
  {
    float dmin = INFINITY;
    #pragma unroll
    for (int s = 0; s < 64; ++s) dmin = fminf(dmin, d[s]);
    dmin = waveMinF(dmin);

    unsigned lo = fkey(dmin);              // cnt(d < dmin) == 0 < 33
    unsigned hi = fkey(4.5f);              // all real dists <= 4 -> cnt >= 33
    int c = 0; bool have = false; float pvx = 0.f;

    while (hi - lo > 1u){
      float loV = fkey_inv(lo), hiV = fkey_inv(hi);
      unsigned mid = fkey(0.5f * (loV + hiV));       // value-space pivot
      mid = (mid <= lo) ? lo + 1u : ((mid >= hi) ? hi - 1u : mid);
      float pv = fkey_inv(mid);
      int cc = 0;
      #pragma unroll
      for (int s = 0; s < 64; ++s) cc += (d[s] < pv) ? 1 : 0;
      cc = waveSumI(cc);
      if (cc < KSEL + 1) lo = mid;
      else { hi = mid; if (cc <= CAND){ c = cc; have = true; pvx = pv; break; } }
    }

    if (have){
      #pragma unroll
      for (int s = 0; s < 64; ++s){
        if (d[s] < pvx){
          int ix = atomicAdd(&ccnt[w], 1);
          if (ix < CAND) cand[w][ix] = d[s];
        }
      }
      __threadfence_block();
      #pragma unroll
      for (int m = 0; m < 3; ++m){
        int idx = lane + 64 * m;
        if (idx < c){
          float v = cand[w][idx];
          int rank = 0;
          for (int q2 = 0; q2 < c; ++q2){
            float cq = cand[w][q2];                  // LDS broadcast
            rank += (cq < v) || (cq == v && q2 < idx);
          }
          if (rank == KSEL) thrSh[w] = v;            // unique-winner mailbox
        }
      }
      __threadfence_block();
      thr = thrSh[w];
    } else {
      thr = fkey_inv(lo);                            // exact 33rd smallest
    }
  }

  // ---- phase 5: logits for row w (strict '<', diag is INF)
  {
    const int tw = tgt[i0 + w];
    float pls = 0.f, nls = 0.f; int pcnt = 0;
    #pragma unroll
    for (int u = 0; u < 16; ++u){
      int4 tg = ((const int4*)tgt)[64 * u + lane];
      #pragma unroll
      for (int q = 0; q < 4; ++q){
        float dvq = d[4*u + q];
        int   tjq = (q==0)?tg.x:(q==1)?tg.y:(q==2)?tg.z:tg.w;
        if (dvq < thr){
          float e = expf(ALPHA_C * (base - dvq));
          if (tjq == tw){ pls += e; pcnt++; } else nls += e;
        }
      }
    }
    pls = waveSumF(pls); nls = waveSumF(nls); pcnt = waveSumI(pcnt);
    if (lane == 0){
      float plogit = (pcnt > 0) ? pls : expf(ALPHA_C * (base - minpos));
      float li = -logf(plogit / (plogit + nls));
      lsSh[w] = li;
      acSh[w] = (li < 0.6f) ? 1.f : 0.f;
    }
  }
  __syncthreads();
  if (tid == 0){
    float ls = 0.f, ac = 0.f;
    #pragma unroll
    for (int r = 0; r < RPB; ++r){ ls += lsSh[r]; ac += acSh[r]; }
    atomicAdd(&accum[0], (double)ls);
    atomicAdd(&accum[1], (double)ac);
    __threadfence();
    unsigned done = atomicAdd(ctr, 1u);
    if (done == gridDim.x - 1){
      double a0 = atomicAdd(&accum[0], 0.0);
      double a1 = atomicAdd(&accum[1], 0.0);
      double a2 = atomicAdd(&accum[2], 0.0);
      double a3 = atomicAdd(&accum[3], 0.0);
      out[0] = (float)(a0 / (double)N);
      out[1] = (float)(a1 / (double)N);
      out[2] = (float)(a2 / ((double)N * 7.0));
      out[3] = (float)(a3 / ((double)N * (double)(N - 8)));
    }
  }
}

// --- fallback (ws too small for dist scratch): R5 register-transpose kernel
__global__ __launch_bounds__(NT, 3) void kmain_reg(const float* __restrict__ xn,
                                                   const float* __restrict__ xnT,
                                                   const float* __restrict__ sq,
                                                   const int* __restrict__ tgt,
                                                   double* __restrict__ accum,
                                                   unsigned* __restrict__ ctr,
                                                   float* __restrict__ out){
  __shared__ float xi[RPB][D];
  __shared__ float buf[2][RPB][256];
  __shared__ float cand[RPB][CAND];
  __shared__ int   ccnt[RPB];
  __shared__ float scrB[RPB][RPB];
  __shared__ float scrM[RPB][RPB];
  __shared__ float scrP[RPB], scrN[RPB], lsSh[RPB], acSh[RPB];

  const int tid  = threadIdx.x;
  const int lane = tid & 63;
  const int w    = tid >> 6;
  const int i0   = blockIdx.x * RPB;

  for (int t = tid; t < RPB * D; t += NT)
    (&xi[0][0])[t] = xn[(size_t)i0 * D + t];
  if (lane == 0){
    ccnt[w] = 0;
    #pragma unroll
    for (int t = 0; t < RPB; ++t){ scrB[w][t] = 0.f; scrM[w][t] = INFINITY; }
  }
  __syncthreads();

  const float4* T4 = (const float4*)xnT;
  float d[64];
  float posd = 0.f, negd = 0.f;

  #pragma unroll
  for (int h = 0; h < 2; ++h){
    const int f = 128 * w + 64 * h + lane;
    float acc[RPB][4];
    #pragma unroll
    for (int r = 0; r < RPB; ++r)
      #pragma unroll
      for (int q = 0; q < 4; ++q) acc[r][q] = 0.f;

    for (int k = 0; k < D; ++k){
      float4 v = T4[(size_t)k * (N/4) + f];
      float xik[RPB];
      #pragma unroll
      for (int r = 0; r < RPB; ++r) xik[r] = xi[r][k];
      #pragma unroll
      for (int r = 0; r < RPB; ++r){
        acc[r][0] += xik[r] * v.x;  acc[r][1] += xik[r] * v.y;
        acc[r][2] += xik[r] * v.z;  acc[r][3] += xik[r] * v.w;
      }
    }

    const float4 sq4 = ((const float4*)sq)[f];
    const int4   tg4 = ((const int4*)tgt)[f];
    const int jbase = 4 * f;

    #pragma unroll
    for (int t = 0; t < RPB; ++t){
      const int A = t & 1;
      const float sqi_t = sq[i0 + t];
      const int   ti_t  = tgt[i0 + t];
      float dv[4]; float pb = 0.f, pm = INFINITY;
      #pragma unroll
      for (int q = 0; q < 4; ++q){
        float sqjq = (q==0)?sq4.x:(q==1)?sq4.y:(q==2)?sq4.z:sq4.w;
        int   tjq  = (q==0)?tg4.x:(q==1)?tg4.y:(q==2)?tg4.z:tg4.w;
        float dj = sqi_t + sqjq - 2.0f * acc[t][q];
        pb += dj;
        bool same = (tjq == ti_t);
        bool diag = (jbase + q == i0 + t);
        if (same && !diag){ posd += dj; pm = fminf(pm, dj); }
        if (!same) negd += dj;
        dv[q] = diag ? INFINITY : dj;
      }
      float rb = waveSumF(pb);
      float rm = waveMinF(pm);
      if (lane == 0){ scrB[w][t] += rb; scrM[w][t] = fminf(scrM[w][t], rm); }
      ((float4*)&buf[A][w][4*lane])[0] = make_float4(dv[0], dv[1], dv[2], dv[3]);
      __syncthreads();
      if (w == t){
        #pragma unroll
        for (int wp = 0; wp < RPB; ++wp){
          float4 v = ((const float4*)&buf[A][wp][4*lane])[0];
          d[4*(2*wp + h) + 0] = v.x;  d[4*(2*wp + h) + 1] = v.y;
          d[4*(2*wp + h) + 2] = v.z;  d[4*(2*wp + h) + 3] = v.w;
        }
      }
    }
  }

  { float v = waveSumF(posd); if (lane == 0) scrP[w] = v; }
  { float v = waveSumF(negd); if (lane == 0) scrN[w] = v; }
  __syncthreads();

  float base, minpos;
  {
    float bp = (lane < 8) ? scrB[lane][w] : 0.f;
    base = waveSumF(bp) * (1.0f / (float)N);
    float mp = (lane < 8) ? scrM[lane][w] : INFINITY;
    minpos = waveMinF(mp);
  }
  if (tid == 0){
    double sp = 0.0, sn = 0.0;
    #pragma unroll
    for (int r = 0; r < RPB; ++r){ sp += (double)scrP[r]; sn += (double)scrN[r]; }
    atomicAdd(&accum[2], sp);
    atomicAdd(&accum[3], sn);
  }

  float thr;
  {
    float dmin = INFINITY;
    #pragma unroll
    for (int s = 0; s < 64; ++s) dmin = fminf(dmin, d[s]);
    dmin = waveMinF(dmin);
    unsigned lo = fkey(dmin);
    unsigned hi = fkey(4.5f);
    int c = 0; bool have = false; float pvx = 0.f;
    while (hi - lo > 1u){
      float loV = fkey_inv(lo), hiV = fkey_inv(hi);
      unsigned mid = fkey(0.5f * (loV + hiV));
      mid = (mid <= lo) ? lo + 1u : ((mid >= hi) ? hi - 1u : mid);
      float pv = fkey_inv(mid);
      int cc = 0;
      #pragma unroll
      for (int s = 0; s < 64; ++s) cc += (d[s] < pv) ? 1 : 0;
      cc = waveSumI(cc);
      if (cc < KSEL + 1) lo = mid;
      else { hi = mid; if (cc <= CAND){ c = cc; have = true; pvx = pv; break; } }
    }
    if (have){
      #pragma unroll
      for (int s = 0; s < 64; ++s){
        if (d[s] < pvx){
          int ix = atomicAdd(&ccnt[w], 1);
          if (ix < CAND) cand[w][ix] = d[s];
        }
      }
      __threadfence_block();
      #pragma unroll
      for (int m = 0; m < 3; ++m){
        int idx = lane + 64 * m;
        if (idx < c){
          float v = cand[w][idx];
          int rank = 0;
          for (int q2 = 0; q2 < c; ++q2){
            float cq = cand[w][q2];
            rank += (cq < v) || (cq == v && q2 < idx);
          }
          if (rank == KSEL) lsSh[w] = v;
        }
      }
      __threadfence_block();
      thr = lsSh[w];
    } else {
      thr = fkey_inv(lo);
    }
  }

  {
    const int tw = tgt[i0 + w];
    float pls = 0.f, nls = 0.f; int pcnt = 0;
    #pragma unroll
    for (int u = 0; u < 16; ++u){
      int4 tg = ((const int4*)tgt)[64 * u + lane];
      #pragma unroll
      for (int q = 0; q < 4; ++q){
        float dvq = d[4*u + q];
        int   tjq = (q==0)?tg.x:(q==1)?tg.y:(q==2)?tg.z:tg.w;
        if (dvq < thr){
          float e = expf(ALPHA_C * (base - dvq));
          if (tjq == tw){ pls += e; pcnt++; } else nls += e;
        }
      }
    }
    pls = waveSumF(pls); nls = waveSumF(nls); pcnt = waveSumI(pcnt);
    if (lane == 0){
      float plogit = (pcnt > 0) ? pls : expf(ALPHA_C * (base - minpos));
      float li = -logf(plogit / (plogit + nls));
      lsSh[w] = li;
      acSh[w] = (li < 0.6f) ? 1.f : 0.f;
    }
  }
  __syncthreads();
  if (tid == 0){
    float ls = 0.f, ac = 0.f;
    #pragma unroll
    for (int r = 0; r < RPB; ++r){ ls += lsSh[r]; ac += acSh[r]; }
    atomicAdd(&accum[0], (double)ls);
    atomicAdd(&accum[1], (double)ac);
    __threadfence();
    unsigned done = atomicAdd(ctr, 1u);
    if (done == gridDim.x - 1){
      double a0 = atomicAdd(&accum[0], 0.0);
      double a1 = atomicAdd(&accum[1], 0.0);
      double a2 = atomicAdd(&accum[2], 0.0);
      double a3 = atomicAdd(&accum[3], 0.0);
      out[0] = (float)(a0 / (double)N);
      out[1] = (float)(a1 / (double)N);
      out[2] = (float)(a2 / ((double)N * 7.0));
      out[3] = (float)(a3 / ((double)N * (double)(N - 8)));
    }
  }
}

extern "C" void kernel_launch(void* const* d_in, const int* in_sizes, int n_in,
                              void* d_out, int out_size, void* d_ws, size_t ws_size,
                              hipStream_t stream){
  (void)in_sizes; (void)n_in; (void)out_size;
  const float* in  = (const float*)d_in[0];
  const int*   tgt = (const int*)d_in[1];
  float* out = (float*)d_out;

  char* ws = (char*)d_ws;
  float*    xn    = (float*)(ws);                       // 2 MB
  float*    xnT   = (float*)(ws + 2097152);             // 2 MB
  float*    sq    = (float*)(ws + 4194304);             // 16 KB
  double*   accum = (double*)(ws + 4210688);            // 32 B (8-aligned)
  unsigned* ctr   = (unsigned*)(ws + 4210720);          // 4 B
  float*    dist  = (float*)(ws + 4210944);             // 64 MB (256-aligned)
  const size_t need = 4210944ull + (size_t)N * N * 4ull;

  knorm<<<N/KROWS, 256, 0, stream>>>(in, xn, xnT, sq, accum, ctr);
  if (ws_size >= need)
    kmain<<<N/RPB, NT, 0, stream>>>(xn, xnT, sq, tgt, dist, accum, ctr, out);
  else
    kmain_reg<<<N/RPB, NT, 0, stream>>>(xn, xnT, sq, tgt, accum, ctr, out);
}

// Round 8
// 174.677 us; speedup vs baseline: 1.3875x; 1.0762x over previous
//
#include <hip/hip_runtime.h>
#include <math.h>

#define N 4096
#define D 128
#define KSEL 32          // 0-indexed order statistic (33rd smallest)
#define CAND 192         // collect band (KSEL, CAND]
#define ALPHA_C 16.0f

typedef short bf16x8 __attribute__((ext_vector_type(8)));
typedef float f32x4  __attribute__((ext_vector_type(4)));

__device__ inline float waveSumF(float v){
  #pragma unroll
  for (int o = 32; o; o >>= 1) v += __shfl_xor(v, o);
  return v;
}
__device__ inline int waveSumI(int v){
  #pragma unroll
  for (int o = 32; o; o >>= 1) v += __shfl_xor(v, o);
  return v;
}
__device__ inline float waveMinF(float v){
  #pragma unroll
  for (int o = 32; o; o >>= 1) v = fminf(v, __shfl_xor(v, o));
  return v;
}
// order-preserving float<->uint key (monotone bijection)
__device__ inline unsigned fkey(float f){
  unsigned u = __float_as_uint(f);
  return u ^ ((u >> 31) ? 0xFFFFFFFFu : 0x80000000u);
}
__device__ inline float fkey_inv(unsigned u){
  unsigned bits = (u & 0x80000000u) ? (u ^ 0x80000000u) : ~u;
  return __uint_as_float(bits);
}
// fp32 -> bf16 bits, round-to-nearest-even (values are finite, ~0.1 scale)
__device__ inline unsigned short f2bf(float x){
  unsigned u = __float_as_uint(x);
  return (unsigned short)((u + 0x7FFFu + ((u >> 16) & 1u)) >> 16);
}
__device__ inline float bf2f(unsigned short h){
  return __uint_as_float(((unsigned)h) << 16);
}

// --- kernel 1: normalize; emit bf16 hi/lo split (row-major) + sq; zero accum
__global__ __launch_bounds__(256) void knorm(const float* __restrict__ in,
                                             unsigned short* __restrict__ xh,
                                             unsigned short* __restrict__ xl,
                                             float* __restrict__ sq,
                                             double* __restrict__ accum,
                                             unsigned* __restrict__ ctr){
  if (blockIdx.x == 0 && threadIdx.x < 5){
    if (threadIdx.x < 4) accum[threadIdx.x] = 0.0;
    else *ctr = 0u;
  }
  const int row  = blockIdx.x * 4 + (threadIdx.x >> 6);
  const int lane = threadIdx.x & 63;
  const float* p = in + (size_t)row * D;
  float e0 = p[lane], e1 = p[lane + 64];
  float s = waveSumF(e0*e0 + e1*e1);
  float inv = 1.0f / sqrtf(s);
  float x0 = e0 * inv, x1 = e1 * inv;
  float s2 = waveSumF(x0*x0 + x1*x1);      // faithful: sq from normalized x
  unsigned short h0 = f2bf(x0);  unsigned short l0 = f2bf(x0 - bf2f(h0));
  unsigned short h1 = f2bf(x1);  unsigned short l1 = f2bf(x1 - bf2f(h1));
  xh[(size_t)row * D + lane]      = h0;
  xh[(size_t)row * D + lane + 64] = h1;
  xl[(size_t)row * D + lane]      = l0;
  xl[(size_t)row * D + lane + 64] = l1;
  if (lane == 0) sq[row] = s2;
}

// --- kernel 2: MFMA Gram tiles (128x128 per block), dist -> global scratch.
// No LDS, no barriers: fragments read straight from L2-resident xh/xl.
// 16x16x32 bf16 convention (m89-verified family): A-frag lane l = row (l&15),
// k = 32*ks + (l>>4)*8 + e ; B-frag lane l = col (l&15), same k ;
// C/D: col = l&15, row = 4*(l>>4) + reg.
__global__ __launch_bounds__(512, 3) void kdot(const unsigned short* __restrict__ xh,
                                               const unsigned short* __restrict__ xl,
                                               const float* __restrict__ sq,
                                               float* __restrict__ dist){
  const int lane = threadIdx.x & 63;
  const int w    = threadIdx.x >> 6;      // 8 waves: 2 (rows) x 4 (cols)
  const int wr   = w >> 2, wc = w & 3;
  const int i0   = blockIdx.y * 128;
  const int j0   = blockIdx.x * 128;

  const int rA = i0 + 64*wr + (lane & 15);  // + 16*tr
  const int cB = j0 + 32*wc + (lane & 15);  // + 16*tc
  const int kb = (lane >> 4) * 8;           // + 32*ks

  f32x4 acc[4][2];
  #pragma unroll
  for (int tr = 0; tr < 4; ++tr)
    #pragma unroll
    for (int tc = 0; tc < 2; ++tc) acc[tr][tc] = (f32x4){0.f,0.f,0.f,0.f};

  #pragma unroll
  for (int ks = 0; ks < 4; ++ks){
    const int k = 32*ks + kb;
    bf16x8 ah[4], al[4], bh[2], bl[2];
    #pragma unroll
    for (int tr = 0; tr < 4; ++tr){
      ah[tr] = *(const bf16x8*)(xh + (size_t)(rA + 16*tr) * D + k);
      al[tr] = *(const bf16x8*)(xl + (size_t)(rA + 16*tr) * D + k);
    }
    #pragma unroll
    for (int tc = 0; tc < 2; ++tc){
      bh[tc] = *(const bf16x8*)(xh + (size_t)(cB + 16*tc) * D + k);
      bl[tc] = *(const bf16x8*)(xl + (size_t)(cB + 16*tc) * D + k);
    }
    #pragma unroll
    for (int tr = 0; tr < 4; ++tr)
      #pragma unroll
      for (int tc = 0; tc < 2; ++tc){
        acc[tr][tc] = __builtin_amdgcn_mfma_f32_16x16x32_bf16(ah[tr], bh[tc], acc[tr][tc], 0, 0, 0);
        acc[tr][tc] = __builtin_amdgcn_mfma_f32_16x16x32_bf16(ah[tr], bl[tc], acc[tr][tc], 0, 0, 0);
        acc[tr][tc] = __builtin_amdgcn_mfma_f32_16x16x32_bf16(al[tr], bh[tc], acc[tr][tc], 0, 0, 0);
      }
  }

  // epilogue: dist = sq_i + sq_j - 2*dot (true value stored at diag too)
  const int i_base = i0 + 64*wr + 4*(lane >> 4);
  const int j_base = j0 + 32*wc + (lane & 15);
  #pragma unroll
  for (int tr = 0; tr < 4; ++tr){
    #pragma unroll
    for (int reg = 0; reg < 4; ++reg){
      const int i = i_base + 16*tr + reg;
      const float sqi = sq[i];
      #pragma unroll
      for (int tc = 0; tc < 2; ++tc){
        const int j = j_base + 16*tc;
        dist[(size_t)i * N + j] = sqi + sq[j] - 2.0f * acc[tr][tc][reg];
      }
    }
  }
}

// --- kernel 3: per-row stats + exact selection + logits (wave per row)
__global__ __launch_bounds__(512, 4) void ksel(const float* __restrict__ dist,
                                               const int* __restrict__ tgt,
                                               double* __restrict__ accum,
                                               unsigned* __restrict__ ctr,
                                               float* __restrict__ out){
  __shared__ float cand[8][CAND];
  __shared__ int   ccnt[8];
  __shared__ float scrP[8], scrN[8], thrSh[8], lsSh[8], acSh[8];

  const int tid  = threadIdx.x;
  const int lane = tid & 63;
  const int w    = tid >> 6;
  const int r    = blockIdx.x * 8 + w;    // owned row

  if (lane == 0) ccnt[w] = 0;
  __syncthreads();

  const int tw = tgt[r];
  const float4* drow = (const float4*)(dist + (size_t)r * N);
  const int4*   tg4  = (const int4*)tgt;

  // load row + fused stats (bsum over true values incl. diag; diag->INF in d)
  float d[64];
  float pb = 0.f, posd = 0.f, negd = 0.f, pm = INFINITY;
  #pragma unroll
  for (int u = 0; u < 16; ++u){
    float4 v = drow[64*u + lane];
    int4  tg = tg4 [64*u + lane];
    const int jb = 4*(64*u + lane);
    #pragma unroll
    for (int q = 0; q < 4; ++q){
      float dj = (q==0)?v.x:(q==1)?v.y:(q==2)?v.z:v.w;
      int   tj = (q==0)?tg.x:(q==1)?tg.y:(q==2)?tg.z:tg.w;
      const bool diag = (jb + q == r);
      pb += dj;                            // base includes true diag value (ref)
      const bool same = (tj == tw);
      if (same && !diag){ posd += dj; pm = fminf(pm, dj); }
      if (!same) negd += dj;
      d[4*u + q] = diag ? INFINITY : dj;
    }
  }
  const float base   = waveSumF(pb) * (1.0f / (float)N);
  const float minpos = waveMinF(pm);
  { float v = waveSumF(posd); if (lane == 0) scrP[w] = v; }
  { float v = waveSumF(negd); if (lane == 0) scrN[w] = v; }

  // selection from registers (R6-proven exact logic)
  float thr;
  {
    float dmin = INFINITY;
    #pragma unroll
    for (int s = 0; s < 64; ++s) dmin = fminf(dmin, d[s]);
    dmin = waveMinF(dmin);

    unsigned lo = fkey(dmin);              // cnt(d < dmin) == 0 < 33
    unsigned hi = fkey(4.5f);              // all real dists <= 4+eps -> cnt >= 33
    int c = 0; bool have = false; float pvx = 0.f;

    while (hi - lo > 1u){
      float loV = fkey_inv(lo), hiV = fkey_inv(hi);
      unsigned mid = fkey(0.5f * (loV + hiV));       // value-space pivot
      mid = (mid <= lo) ? lo + 1u : ((mid >= hi) ? hi - 1u : mid);
      float pv = fkey_inv(mid);
      int cc = 0;
      #pragma unroll
      for (int s = 0; s < 64; ++s) cc += (d[s] < pv) ? 1 : 0;
      cc = waveSumI(cc);
      if (cc < KSEL + 1) lo = mid;
      else { hi = mid; if (cc <= CAND){ c = cc; have = true; pvx = pv; break; } }
    }

    if (have){
      #pragma unroll
      for (int s = 0; s < 64; ++s){
        if (d[s] < pvx){
          int ix = atomicAdd(&ccnt[w], 1);
          if (ix < CAND) cand[w][ix] = d[s];
        }
      }
      __threadfence_block();
      #pragma unroll
      for (int m = 0; m < 3; ++m){
        int idx = lane + 64 * m;
        if (idx < c){
          float v = cand[w][idx];
          int rank = 0;
          for (int q2 = 0; q2 < c; ++q2){
            float cq = cand[w][q2];                  // LDS broadcast
            rank += (cq < v) || (cq == v && q2 < idx);
          }
          if (rank == KSEL) thrSh[w] = v;            // unique-winner mailbox
        }
      }
      __threadfence_block();
      thr = thrSh[w];
    } else {
      thr = fkey_inv(lo);                            // exact 33rd smallest
    }
  }

  // logits (strict '<', diag is INF)
  {
    float pls = 0.f, nls = 0.f; int pcnt = 0;
    #pragma unroll
    for (int u = 0; u < 16; ++u){
      int4 tg = tg4[64*u + lane];
      #pragma unroll
      for (int q = 0; q < 4; ++q){
        float dvq = d[4*u + q];
        int   tj  = (q==0)?tg.x:(q==1)?tg.y:(q==2)?tg.z:tg.w;
        if (dvq < thr){
          float e = expf(ALPHA_C * (base - dvq));
          if (tj == tw){ pls += e; pcnt++; } else nls += e;
        }
      }
    }
    pls = waveSumF(pls); nls = waveSumF(nls); pcnt = waveSumI(pcnt);
    if (lane == 0){
      float plogit = (pcnt > 0) ? pls : expf(ALPHA_C * (base - minpos));
      float li = -logf(plogit / (plogit + nls));
      lsSh[w] = li;
      acSh[w] = (li < 0.6f) ? 1.f : 0.f;
    }
  }
  __syncthreads();
  if (tid == 0){
    float ls = 0.f, ac = 0.f; double sp = 0.0, sn = 0.0;
    #pragma unroll
    for (int q = 0; q < 8; ++q){
      ls += lsSh[q]; ac += acSh[q];
      sp += (double)scrP[q]; sn += (double)scrN[q];
    }
    atomicAdd(&accum[0], (double)ls);
    atomicAdd(&accum[1], (double)ac);
    atomicAdd(&accum[2], sp);
    atomicAdd(&accum[3], sn);
    __threadfence();
    unsigned done = atomicAdd(ctr, 1u);
    if (done == gridDim.x - 1){
      double a0 = atomicAdd(&accum[0], 0.0);
      double a1 = atomicAdd(&accum[1], 0.0);
      double a2 = atomicAdd(&accum[2], 0.0);
      double a3 = atomicAdd(&accum[3], 0.0);
      out[0] = (float)(a0 / (double)N);
      out[1] = (float)(a1 / (double)N);
      out[2] = (float)(a2 / ((double)N * 7.0));
      out[3] = (float)(a3 / ((double)N * (double)(N - 8)));
    }
  }
}

extern "C" void kernel_launch(void* const* d_in, const int* in_sizes, int n_in,
                              void* d_out, int out_size, void* d_ws, size_t ws_size,
                              hipStream_t stream){
  (void)in_sizes; (void)n_in; (void)out_size; (void)ws_size;
  const float* in  = (const float*)d_in[0];
  const int*   tgt = (const int*)d_in[1];
  float* out = (float*)d_out;

  char* ws = (char*)d_ws;
  unsigned short* xh = (unsigned short*)(ws);            // 1 MB
  unsigned short* xl = (unsigned short*)(ws + 1048576);  // 1 MB
  float*    sq    = (float*)(ws + 2097152);              // 16 KB
  double*   accum = (double*)(ws + 2113536);             // 32 B (8-aligned)
  unsigned* ctr   = (unsigned*)(ws + 2113568);           // 4 B
  float*    dist  = (float*)(ws + 2113792);              // 64 MiB (256-aligned)

  knorm<<<N/4, 256, 0, stream>>>(in, xh, xl, sq, accum, ctr);
  dim3 g(N/128, N/128);
  kdot <<<g, 512, 0, stream>>>(xh, xl, sq, dist);
  ksel <<<N/8, 512, 0, stream>>>(dist, tgt, accum, ctr, out);
}